// Round 1
// baseline (1327.313 us; speedup 1.0000x reference)
//
#include <hip/hip_runtime.h>
#include <hip/hip_bf16.h>
#include <stdint.h>

#define NCLS 19
#define HW   (768 * 768)          // 589824
#define NIMG 8
#define NPIX (NIMG * HW)          // 4718592
#define MINKEPT 131072u
#define NBINS 8192

// workspace layout (bytes)
#define OFF_PROB  ((size_t)0)
#define OFF_LOSS  ((size_t)NPIX * 4)
#define OFF_HIST  ((size_t)NPIX * 8)                 // 37,748,736
#define OFF_STATE (OFF_HIST + (size_t)NBINS * 4)     // +32768
#define OFF_ACC   (OFF_STATE + 64)                   // 8-aligned
// state[0]=n_valid  state[1]=k_rem  state[2]=threshold bits  state[3]=prefix

// ---------------------------------------------------------------------------
// K1: fused log-softmax + gather + loss; emit prob bit-pattern (+inf sentinel
// for ignored) and weighted loss; count valid pixels.
__global__ __launch_bounds__(256) void k_main(
    const float* __restrict__ predict, const int* __restrict__ target,
    const float* __restrict__ weight, unsigned* __restrict__ probbits,
    float* __restrict__ lossbuf, unsigned* __restrict__ state)
{
    int g = blockIdx.x * 256 + threadIdx.x;           // grid covers NPIX exactly
    int n = g / HW;
    int p = g - n * HW;
    const float* base = predict + (size_t)n * ((size_t)NCLS * HW) + p;

    float v[NCLS];
#pragma unroll
    for (int c = 0; c < NCLS; ++c) v[c] = base[(size_t)c * HW];

    float m = v[0];
#pragma unroll
    for (int c = 1; c < NCLS; ++c) m = fmaxf(m, v[c]);

    float s = 0.f;
#pragma unroll
    for (int c = 0; c < NCLS; ++c) s += __expf(v[c] - m);

    int t = target[g];
    bool valid = (t != -1);
    int tc = valid ? t : 0;

    // dynamic extract via cndmask chain (no scratch spill)
    float vt = v[0];
#pragma unroll
    for (int c = 1; c < NCLS; ++c) vt = (c == tc) ? v[c] : vt;

    float logp = vt - m - __logf(s);
    float prob = __expf(logp);

    probbits[g] = valid ? __float_as_uint(prob) : 0x7F800000u;  // +inf sentinel
    lossbuf[g]  = valid ? (-weight[tc] * logp) : 0.f;

    unsigned long long b = __ballot(valid);
    if ((threadIdx.x & 63) == 0)
        atomicAdd(&state[0], (unsigned)__popcll(b));
}

// ---------------------------------------------------------------------------
// Histogram pass for radix-select level 0/1/2. LDS hist, flush nonzero only.
__global__ __launch_bounds__(256) void k_hist(
    const unsigned* __restrict__ probbits, unsigned* __restrict__ hist,
    const unsigned* __restrict__ state, int level)
{
    __shared__ unsigned h[NBINS];
    for (int i = threadIdx.x; i < NBINS; i += 256) h[i] = 0;
    __syncthreads();

    unsigned pref = (level == 0) ? 0u : state[3];
    int stride = gridDim.x * 256;
    for (int i = blockIdx.x * 256 + threadIdx.x; i < NPIX; i += stride) {
        unsigned pb = probbits[i];
        if (level == 0) {
            atomicAdd(&h[pb >> 19], 1u);
        } else if (level == 1) {
            if ((pb >> 19) == pref) atomicAdd(&h[(pb >> 6) & (NBINS - 1)], 1u);
        } else {
            if ((pb >> 6) == pref) atomicAdd(&h[pb & 63u], 1u);
        }
    }
    __syncthreads();
    for (int i = threadIdx.x; i < NBINS; i += 256) {
        unsigned c = h[i];
        if (c) atomicAdd(&hist[i], c);
    }
}

// ---------------------------------------------------------------------------
// Single-block scan: find the bin containing the k-th value, update state,
// zero the histogram for the next level.
__global__ __launch_bounds__(256) void k_scan(
    unsigned* __restrict__ hist, unsigned* __restrict__ state, int level)
{
    __shared__ unsigned h[NBINS];
    __shared__ unsigned wtot[4], wpre[4];
    int tid = threadIdx.x;
    for (int i = tid; i < NBINS; i += 256) h[i] = hist[i];
    __syncthreads();

    unsigned vals[32];
    unsigned s = 0;
#pragma unroll
    for (int j = 0; j < 32; ++j) { vals[j] = h[tid * 32 + j]; s += vals[j]; }

    // 256-wide exclusive prefix of chunk sums: shfl wave scan + wave totals
    unsigned x = s;
    int lane = tid & 63, wid = tid >> 6;
    for (int d = 1; d < 64; d <<= 1) {
        unsigned y = __shfl_up(x, d);
        if (lane >= d) x += y;
    }
    if (lane == 63) wtot[wid] = x;
    __syncthreads();
    if (tid == 0) {
        unsigned a = 0;
        for (int i = 0; i < 4; ++i) { wpre[i] = a; a += wtot[i]; }
    }
    __syncthreads();
    unsigned excl = x + wpre[wid] - s;

    unsigned k;
    if (level == 0) {
        unsigned nv = state[0];
        unsigned km = nv - 1u;
        k = (MINKEPT < km) ? MINKEPT : km;
    } else {
        k = state[1];
    }

    if (s > 0 && k >= excl && k < excl + s) {            // exactly one owner
        unsigned rem = k - excl;
        unsigned cum = 0, kn = 0; int bsel = 0; bool found = false;
#pragma unroll
        for (int j = 0; j < 32; ++j) {
            if (!found && rem < cum + vals[j]) { bsel = j; kn = rem - cum; found = true; }
            cum += vals[j];
        }
        unsigned bin = (unsigned)(tid * 32 + bsel);
        if (level == 0)      { state[3] = bin;                       state[1] = kn; }
        else if (level == 1) { state[3] = (state[3] << 13) | bin;    state[1] = kn; }
        else {
            unsigned tb = (state[3] << 6) | bin;         // exact k-th order stat bits
            float thr = fmaxf(__uint_as_float(tb), 0.9f);
            state[2] = __float_as_uint(thr);
        }
    }
    __syncthreads();
    for (int i = tid; i < NBINS; i += 256) hist[i] = 0;  // ready for next level
}

// ---------------------------------------------------------------------------
// Final selection + weighted sum (uint compare == float compare for +floats).
__global__ __launch_bounds__(256) void k_reduce(
    const unsigned* __restrict__ probbits, const float* __restrict__ lossbuf,
    const unsigned* __restrict__ state, double* __restrict__ acc,
    unsigned* __restrict__ cnt)
{
    unsigned tb = state[2];
    double s = 0.0; unsigned c = 0;
    int stride = gridDim.x * 256;
    for (int i = blockIdx.x * 256 + threadIdx.x; i < NPIX; i += stride) {
        unsigned pb = probbits[i];
        float l = lossbuf[i];
        if (pb < tb) { s += (double)l; c++; }
    }
#pragma unroll
    for (int d = 32; d > 0; d >>= 1) {
        s += __shfl_down(s, d);
        c += __shfl_down(c, d);
    }
    __shared__ double sd[4];
    __shared__ unsigned cd[4];
    int lane = threadIdx.x & 63, wid = threadIdx.x >> 6;
    if (lane == 0) { sd[wid] = s; cd[wid] = c; }
    __syncthreads();
    if (threadIdx.x == 0) {
        double st = sd[0] + sd[1] + sd[2] + sd[3];
        unsigned ct = cd[0] + cd[1] + cd[2] + cd[3];
        atomicAdd(acc, st);
        atomicAdd(cnt, ct);
    }
}

__global__ void k_final(const double* __restrict__ acc,
                        const unsigned* __restrict__ cnt,
                        float* __restrict__ out)
{
    out[0] = (float)(acc[0] / (double)cnt[0]);
}

// ---------------------------------------------------------------------------
extern "C" void kernel_launch(void* const* d_in, const int* in_sizes, int n_in,
                              void* d_out, int out_size, void* d_ws, size_t ws_size,
                              hipStream_t stream)
{
    const float* predict = (const float*)d_in[0];
    const int*   target  = (const int*)d_in[1];
    const float* weight  = (const float*)d_in[2];

    char* ws = (char*)d_ws;
    unsigned* probbits = (unsigned*)(ws + OFF_PROB);
    float*    lossbuf  = (float*)(ws + OFF_LOSS);
    unsigned* hist     = (unsigned*)(ws + OFF_HIST);
    unsigned* state    = (unsigned*)(ws + OFF_STATE);
    double*   acc      = (double*)(ws + OFF_ACC);
    unsigned* cnt      = (unsigned*)(ws + OFF_ACC + 8);

    // zero hist + state + accumulators (one memset node; probbits/lossbuf are
    // fully overwritten by k_main before any read)
    hipMemsetAsync(ws + OFF_HIST, 0, (size_t)NBINS * 4 + 64 + 16, stream);

    k_main<<<NPIX / 256, 256, 0, stream>>>(predict, target, weight,
                                           probbits, lossbuf, state);
    k_hist<<<1024, 256, 0, stream>>>(probbits, hist, state, 0);
    k_scan<<<1,    256, 0, stream>>>(hist, state, 0);
    k_hist<<<1024, 256, 0, stream>>>(probbits, hist, state, 1);
    k_scan<<<1,    256, 0, stream>>>(hist, state, 1);
    k_hist<<<1024, 256, 0, stream>>>(probbits, hist, state, 2);
    k_scan<<<1,    256, 0, stream>>>(hist, state, 2);
    k_reduce<<<2048, 256, 0, stream>>>(probbits, lossbuf, state, acc, cnt);
    k_final<<<1, 1, 0, stream>>>(acc, cnt, (float*)d_out);
}

// Round 2
// 566.643 us; speedup vs baseline: 2.3424x; 2.3424x over previous
//
#include <hip/hip_runtime.h>
#include <stdint.h>

#define NCLS 19
#define HW   (768 * 768)          // 589824
#define NPIX (8 * HW)             // 4718592
#define MINKEPT 131072u
#define NBINS 8192

typedef unsigned long long u64;

// workspace layout (bytes)
#define OFF_PROB  ((size_t)0)
#define OFF_LOSS  ((size_t)NPIX * 4)
#define OFF_HIST  ((size_t)NPIX * 8)                 // 37,748,736
#define OFF_STATE (OFF_HIST + (size_t)NBINS * 4)
// state word indices:
//  0: n_valid   1: k_rem   2: thresh_bits   3: prefix   4: flag_common
//  8-9: common_sum (u64, fixed-point 2^20)   10-11: fb_sum (u64)
//  12: common_cnt   13: fb_cnt

// ---------------------------------------------------------------------------
// K1: fused softmax-prob + loss, 4 pixels/thread via float4. Single use per
// loaded value (no rematerialization). Also accumulates the common-path
// (threshold==0.9) selected sum/count and n_valid.
__global__ __launch_bounds__(256) void k_main(
    const float* __restrict__ predict, const int* __restrict__ target,
    const float* __restrict__ weight, unsigned* __restrict__ probbits,
    float* __restrict__ lossbuf, unsigned* __restrict__ state)
{
    int tid = threadIdx.x;
    int g = (blockIdx.x * 256 + tid) * 4;             // first pixel of group
    int n = g / HW;
    int p = g - n * HW;
    const float* base = predict + (size_t)n * ((size_t)NCLS * HW) + p;

    int4 t4 = *(const int4*)(target + g);
    int tcx = (t4.x == -1) ? 0 : t4.x;
    int tcy = (t4.y == -1) ? 0 : t4.y;
    int tcz = (t4.z == -1) ? 0 : t4.z;
    int tcw = (t4.w == -1) ? 0 : t4.w;

    float4 s = {0.f, 0.f, 0.f, 0.f};
    float4 vt = {0.f, 0.f, 0.f, 0.f};
#pragma unroll
    for (int c = 0; c < NCLS; ++c) {
        float4 v = *(const float4*)(base + (size_t)c * HW);
        s.x += __expf(v.x);  s.y += __expf(v.y);
        s.z += __expf(v.z);  s.w += __expf(v.w);
        vt.x = (c == tcx) ? v.x : vt.x;
        vt.y = (c == tcy) ? v.y : vt.y;
        vt.z = (c == tcz) ? v.z : vt.z;
        vt.w = (c == tcw) ? v.w : vt.w;
    }

    bool vx = (t4.x != -1), vy = (t4.y != -1), vz = (t4.z != -1), vw = (t4.w != -1);

    float lpx = vt.x - __logf(s.x);
    float lpy = vt.y - __logf(s.y);
    float lpz = vt.z - __logf(s.z);
    float lpw = vt.w - __logf(s.w);
    float px = __expf(lpx), py = __expf(lpy), pz = __expf(lpz), pw = __expf(lpw);

    uint4 pb;
    pb.x = vx ? __float_as_uint(px) : 0x7F800000u;
    pb.y = vy ? __float_as_uint(py) : 0x7F800000u;
    pb.z = vz ? __float_as_uint(pz) : 0x7F800000u;
    pb.w = vw ? __float_as_uint(pw) : 0x7F800000u;

    float4 lo;
    lo.x = vx ? (-weight[tcx] * lpx) : 0.f;
    lo.y = vy ? (-weight[tcy] * lpy) : 0.f;
    lo.z = vz ? (-weight[tcz] * lpz) : 0.f;
    lo.w = vw ? (-weight[tcw] * lpw) : 0.f;

    *(uint4*)(probbits + g) = pb;
    *(float4*)(lossbuf + g) = lo;

    // common path (threshold == 0.9): selected = valid && prob < 0.9
    bool sx = vx && (px < 0.9f), sy = vy && (py < 0.9f);
    bool sz = vz && (pz < 0.9f), sw = vw && (pw < 0.9f);
    float lsum = (sx ? lo.x : 0.f) + (sy ? lo.y : 0.f) +
                 (sz ? lo.z : 0.f) + (sw ? lo.w : 0.f);
    int scnt = (int)sx + (int)sy + (int)sz + (int)sw;
    int vcnt = (int)vx + (int)vy + (int)vz + (int)vw;

#pragma unroll
    for (int d = 32; d > 0; d >>= 1) {
        lsum += __shfl_down(lsum, d);
        scnt += __shfl_down(scnt, d);
        vcnt += __shfl_down(vcnt, d);
    }
    __shared__ float lss[4];
    __shared__ int scs[4], vcs[4];
    int lane = tid & 63, wid = tid >> 6;
    if (lane == 0) { lss[wid] = lsum; scs[wid] = scnt; vcs[wid] = vcnt; }
    __syncthreads();
    if (tid == 0) {
        float lt = lss[0] + lss[1] + lss[2] + lss[3];
        int st = scs[0] + scs[1] + scs[2] + scs[3];
        int vv = vcs[0] + vcs[1] + vcs[2] + vcs[3];
        atomicAdd((u64*)&state[8], (u64)((double)lt * 1048576.0));
        atomicAdd(&state[12], (unsigned)st);
        atomicAdd(&state[0], (unsigned)vv);
    }
}

// ---------------------------------------------------------------------------
// Decide whether the exact k-th order stat is < 0.9 (=> threshold is 0.9 and
// K1's accumulators are the final answer).
__global__ void k_decide(unsigned* __restrict__ state)
{
    unsigned nv = state[0];
    unsigned km = nv - 1u;
    unsigned k = (MINKEPT < km) ? MINKEPT : km;
    unsigned cb = state[12];                 // count(valid && prob < 0.9)
    state[4] = (cb > k) ? 1u : 0u;
}

// ---------------------------------------------------------------------------
// Fallback radix-select (exact) — early-exits when common path resolved.
__global__ __launch_bounds__(256) void k_hist(
    const unsigned* __restrict__ probbits, unsigned* __restrict__ hist,
    const unsigned* __restrict__ state, int level)
{
    if (state[4]) return;
    __shared__ unsigned h[NBINS];
    for (int i = threadIdx.x; i < NBINS; i += 256) h[i] = 0;
    __syncthreads();

    unsigned pref = (level == 0) ? 0u : state[3];
    int stride = gridDim.x * 256;
    for (int i = blockIdx.x * 256 + threadIdx.x; i < NPIX; i += stride) {
        unsigned pb = probbits[i];
        if (level == 0) {
            atomicAdd(&h[pb >> 19], 1u);
        } else if (level == 1) {
            if ((pb >> 19) == pref) atomicAdd(&h[(pb >> 6) & (NBINS - 1)], 1u);
        } else {
            if ((pb >> 6) == pref) atomicAdd(&h[pb & 63u], 1u);
        }
    }
    __syncthreads();
    for (int i = threadIdx.x; i < NBINS; i += 256) {
        unsigned c = h[i];
        if (c) atomicAdd(&hist[i], c);
    }
}

__global__ __launch_bounds__(256) void k_scan(
    unsigned* __restrict__ hist, unsigned* __restrict__ state, int level)
{
    if (state[4]) return;
    __shared__ unsigned h[NBINS];
    __shared__ unsigned wtot[4], wpre[4];
    int tid = threadIdx.x;
    for (int i = tid; i < NBINS; i += 256) h[i] = hist[i];
    __syncthreads();

    unsigned vals[32];
    unsigned s = 0;
#pragma unroll
    for (int j = 0; j < 32; ++j) { vals[j] = h[tid * 32 + j]; s += vals[j]; }

    unsigned x = s;
    int lane = tid & 63, wid = tid >> 6;
    for (int d = 1; d < 64; d <<= 1) {
        unsigned y = __shfl_up(x, d);
        if (lane >= d) x += y;
    }
    if (lane == 63) wtot[wid] = x;
    __syncthreads();
    if (tid == 0) {
        unsigned a = 0;
        for (int i = 0; i < 4; ++i) { wpre[i] = a; a += wtot[i]; }
    }
    __syncthreads();
    unsigned excl = x + wpre[wid] - s;

    unsigned k;
    if (level == 0) {
        unsigned nv = state[0];
        unsigned km = nv - 1u;
        k = (MINKEPT < km) ? MINKEPT : km;
    } else {
        k = state[1];
    }

    if (s > 0 && k >= excl && k < excl + s) {
        unsigned rem = k - excl;
        unsigned cum = 0, kn = 0; int bsel = 0; bool found = false;
#pragma unroll
        for (int j = 0; j < 32; ++j) {
            if (!found && rem < cum + vals[j]) { bsel = j; kn = rem - cum; found = true; }
            cum += vals[j];
        }
        unsigned bin = (unsigned)(tid * 32 + bsel);
        if (level == 0)      { state[3] = bin;                    state[1] = kn; }
        else if (level == 1) { state[3] = (state[3] << 13) | bin; state[1] = kn; }
        else {
            unsigned tb = (state[3] << 6) | bin;   // exact k-th order stat
            float thr = fmaxf(__uint_as_float(tb), 0.9f);
            state[2] = __float_as_uint(thr);
        }
    }
    __syncthreads();
    for (int i = tid; i < NBINS; i += 256) hist[i] = 0;
}

__global__ __launch_bounds__(256) void k_reduce_fb(
    const unsigned* __restrict__ probbits, const float* __restrict__ lossbuf,
    unsigned* __restrict__ state)
{
    if (state[4]) return;
    unsigned tb = state[2];
    float s = 0.f; unsigned c = 0;
    int stride = gridDim.x * 256;
    for (int i = blockIdx.x * 256 + threadIdx.x; i < NPIX; i += stride) {
        unsigned pb = probbits[i];
        float l = lossbuf[i];
        if (pb < tb) { s += l; c++; }
    }
#pragma unroll
    for (int d = 32; d > 0; d >>= 1) {
        s += __shfl_down(s, d);
        c += __shfl_down(c, d);
    }
    __shared__ float sd[4];
    __shared__ unsigned cd[4];
    int lane = threadIdx.x & 63, wid = threadIdx.x >> 6;
    if (lane == 0) { sd[wid] = s; cd[wid] = c; }
    __syncthreads();
    if (threadIdx.x == 0) {
        float st = sd[0] + sd[1] + sd[2] + sd[3];
        unsigned ct = cd[0] + cd[1] + cd[2] + cd[3];
        atomicAdd((u64*)&state[10], (u64)((double)st * 1048576.0));
        atomicAdd(&state[13], ct);
    }
}

__global__ void k_final(const unsigned* __restrict__ state, float* __restrict__ out)
{
    bool common = state[4] != 0;
    u64 su = common ? *(const u64*)&state[8] : *(const u64*)&state[10];
    unsigned cn = common ? state[12] : state[13];
    out[0] = (float)(((double)su / 1048576.0) / (double)cn);
}

// ---------------------------------------------------------------------------
extern "C" void kernel_launch(void* const* d_in, const int* in_sizes, int n_in,
                              void* d_out, int out_size, void* d_ws, size_t ws_size,
                              hipStream_t stream)
{
    const float* predict = (const float*)d_in[0];
    const int*   target  = (const int*)d_in[1];
    const float* weight  = (const float*)d_in[2];

    char* ws = (char*)d_ws;
    unsigned* probbits = (unsigned*)(ws + OFF_PROB);
    float*    lossbuf  = (float*)(ws + OFF_LOSS);
    unsigned* hist     = (unsigned*)(ws + OFF_HIST);
    unsigned* state    = (unsigned*)(ws + OFF_STATE);

    hipMemsetAsync(ws + OFF_HIST, 0, (size_t)NBINS * 4 + 64, stream);

    k_main<<<NPIX / 1024, 256, 0, stream>>>(predict, target, weight,
                                            probbits, lossbuf, state);
    k_decide<<<1, 1, 0, stream>>>(state);
    k_hist<<<1024, 256, 0, stream>>>(probbits, hist, state, 0);
    k_scan<<<1,    256, 0, stream>>>(hist, state, 0);
    k_hist<<<1024, 256, 0, stream>>>(probbits, hist, state, 1);
    k_scan<<<1,    256, 0, stream>>>(hist, state, 1);
    k_hist<<<1024, 256, 0, stream>>>(probbits, hist, state, 2);
    k_scan<<<1,    256, 0, stream>>>(hist, state, 2);
    k_reduce_fb<<<1024, 256, 0, stream>>>(probbits, lossbuf, state);
    k_final<<<1, 1, 0, stream>>>(state, (float*)d_out);
}

// Round 4
// 493.297 us; speedup vs baseline: 2.6907x; 1.1487x over previous
//
#include <hip/hip_runtime.h>
#include <stdint.h>

#define NCLS 19
#define HW   (768 * 768)          // 589824
#define NPIX (8 * HW)             // 4718592
#define NGRP (NPIX / 4)           // 1179648 groups of 4 pixels
#define MINKEPT 131072u
#define NBINS 8192
#define BLOCK 256
#define GRID_MAIN (NGRP / BLOCK)  // 4608 blocks, exactly 1 group per thread

// workspace layout (bytes) — all write-before-read, no memset required
#define OFF_PSUM  ((size_t)0)                          // GRID_MAIN f32 partial sums
#define OFF_PCS   ((size_t)GRID_MAIN * 4)              // GRID_MAIN u32 sel-cnt
#define OFF_PCV   ((size_t)GRID_MAIN * 8)              // GRID_MAIN u32 valid-cnt
#define OFF_STATE ((size_t)GRID_MAIN * 12)             // state words
#define OFF_PROB  (OFF_STATE + 256)                    // NPIX u32  (fallback only)
#define OFF_LOSS  (OFF_PROB + (size_t)NPIX * 4)        // NPIX f32  (fallback only)
#define OFF_HIST  (OFF_LOSS + (size_t)NPIX * 4)        // NBINS u32 (fallback only)
// state: [0]=pref [1]=krem [2]=thresh_bits [4]=flag_common [5]=k

struct Grp { uint4 pb; float4 lo; float ls; unsigned sc; unsigned vc; };

// Pure per-group function — fallback recompute is bit-identical to phase 1.
__device__ __forceinline__ Grp compute4(const float* __restrict__ predict,
                                        const int* __restrict__ target,
                                        const float* __restrict__ wsh, int g)
{
    int n = g / HW;
    int p = g - n * HW;
    const float* base = predict + (size_t)n * ((size_t)NCLS * HW) + p;

    int4 t4 = *(const int4*)(target + g);
    int tcx = (t4.x == -1) ? 0 : t4.x;
    int tcy = (t4.y == -1) ? 0 : t4.y;
    int tcz = (t4.z == -1) ? 0 : t4.z;
    int tcw = (t4.w == -1) ? 0 : t4.w;

    float4 s = {0.f, 0.f, 0.f, 0.f};
    float4 vt = {0.f, 0.f, 0.f, 0.f};
#pragma unroll
    for (int c = 0; c < NCLS; ++c) {
        float4 v = *(const float4*)(base + (size_t)c * HW);
        s.x += __expf(v.x); s.y += __expf(v.y);
        s.z += __expf(v.z); s.w += __expf(v.w);
        vt.x = (c == tcx) ? v.x : vt.x;
        vt.y = (c == tcy) ? v.y : vt.y;
        vt.z = (c == tcz) ? v.z : vt.z;
        vt.w = (c == tcw) ? v.w : vt.w;
    }

    bool vx = (t4.x != -1), vy = (t4.y != -1), vz = (t4.z != -1), vw = (t4.w != -1);
    float lpx = vt.x - __logf(s.x), lpy = vt.y - __logf(s.y);
    float lpz = vt.z - __logf(s.z), lpw = vt.w - __logf(s.w);
    float px = __expf(lpx), py = __expf(lpy), pz = __expf(lpz), pw = __expf(lpw);

    Grp r;
    r.pb.x = vx ? __float_as_uint(px) : 0x7F800000u;
    r.pb.y = vy ? __float_as_uint(py) : 0x7F800000u;
    r.pb.z = vz ? __float_as_uint(pz) : 0x7F800000u;
    r.pb.w = vw ? __float_as_uint(pw) : 0x7F800000u;
    r.lo.x = vx ? (-wsh[tcx] * lpx) : 0.f;
    r.lo.y = vy ? (-wsh[tcy] * lpy) : 0.f;
    r.lo.z = vz ? (-wsh[tcz] * lpz) : 0.f;
    r.lo.w = vw ? (-wsh[tcw] * lpw) : 0.f;
    bool sx = vx && (px < 0.9f), sy = vy && (py < 0.9f);
    bool sz = vz && (pz < 0.9f), sw = vw && (pw < 0.9f);
    r.ls = (sx ? r.lo.x : 0.f) + (sy ? r.lo.y : 0.f) +
           (sz ? r.lo.z : 0.f) + (sw ? r.lo.w : 0.f);
    r.sc = (unsigned)sx + (unsigned)sy + (unsigned)sz + (unsigned)sw;
    r.vc = (unsigned)vx + (unsigned)vy + (unsigned)vz + (unsigned)vw;
    return r;
}

// ---------------------------------------------------------------------------
// K1: pure-read streaming pass. One 4-pixel group per thread; per-block
// partials (no atomics, no stores of probbits/lossbuf).
__global__ __launch_bounds__(BLOCK) void k_main(
    const float* __restrict__ predict, const int* __restrict__ target,
    const float* __restrict__ weight, float* __restrict__ psum,
    unsigned* __restrict__ pcs, unsigned* __restrict__ pcv)
{
    __shared__ float wsh[32];
    __shared__ float red_f[4];
    __shared__ unsigned red_a[4], red_b[4];
    int tid = threadIdx.x, bid = blockIdx.x;
    if (tid < NCLS) wsh[tid] = weight[tid];
    __syncthreads();

    Grp r = compute4(predict, target, wsh, (bid * BLOCK + tid) * 4);
    float lsum = r.ls; unsigned scnt = r.sc, vcnt = r.vc;
#pragma unroll
    for (int d = 32; d > 0; d >>= 1) {
        lsum += __shfl_down(lsum, d);
        scnt += __shfl_down(scnt, d);
        vcnt += __shfl_down(vcnt, d);
    }
    if ((tid & 63) == 0) { red_f[tid >> 6] = lsum; red_a[tid >> 6] = scnt; red_b[tid >> 6] = vcnt; }
    __syncthreads();
    if (tid == 0) {
        psum[bid] = red_f[0] + red_f[1] + red_f[2] + red_f[3];
        pcs[bid]  = red_a[0] + red_a[1] + red_a[2] + red_a[3];
        pcv[bid]  = red_b[0] + red_b[1] + red_b[2] + red_b[3];
    }
}

// ---------------------------------------------------------------------------
// K2: reduce partials; decide path; write output on the common path.
__global__ __launch_bounds__(BLOCK) void k_decide(
    const float* __restrict__ psum, const unsigned* __restrict__ pcs,
    const unsigned* __restrict__ pcv, unsigned* __restrict__ state,
    float* __restrict__ out)
{
    __shared__ double red_d[4];
    __shared__ unsigned red_a[4], red_b[4];
    int tid = threadIdx.x;
    double ds = 0.0; unsigned cs = 0, cv = 0;
    for (int i = tid; i < GRID_MAIN; i += BLOCK) {
        ds += (double)psum[i]; cs += pcs[i]; cv += pcv[i];
    }
#pragma unroll
    for (int d = 32; d > 0; d >>= 1) {
        ds += __shfl_down(ds, d); cs += __shfl_down(cs, d); cv += __shfl_down(cv, d);
    }
    if ((tid & 63) == 0) { red_d[tid >> 6] = ds; red_a[tid >> 6] = cs; red_b[tid >> 6] = cv; }
    __syncthreads();
    if (tid == 0) {
        double sum = red_d[0] + red_d[1] + red_d[2] + red_d[3];
        unsigned cb = red_a[0] + red_a[1] + red_a[2] + red_a[3];
        unsigned nv = red_b[0] + red_b[1] + red_b[2] + red_b[3];
        unsigned km = nv - 1u;
        unsigned k  = (MINKEPT < km) ? MINKEPT : km;
        bool common = cb > k;          // k-th order stat < 0.9 => threshold == 0.9
        state[4] = common ? 1u : 0u;
        state[5] = k;
        if (common) out[0] = (float)(sum / (double)cb);
    }
}

// ---------------------------------------------------------------------------
// Fallback (exact radix-select) — all guarded, early-exit on common path.
__global__ __launch_bounds__(BLOCK) void k_mat(
    const float* __restrict__ predict, const int* __restrict__ target,
    const float* __restrict__ weight, const unsigned* __restrict__ state,
    unsigned* __restrict__ probbits, float* __restrict__ lossbuf,
    unsigned* __restrict__ hist)
{
    if (state[4]) return;
    __shared__ float wsh[32];
    if (threadIdx.x < NCLS) wsh[threadIdx.x] = weight[threadIdx.x];
    __syncthreads();
    int stride = gridDim.x * BLOCK;
    for (int idx = blockIdx.x * BLOCK + threadIdx.x; idx < NGRP; idx += stride) {
        int g = idx * 4;
        Grp r = compute4(predict, target, wsh, g);
        *(uint4*)(probbits + g) = r.pb;
        *(float4*)(lossbuf + g) = r.lo;
    }
    for (int i = blockIdx.x * BLOCK + threadIdx.x; i < NBINS; i += stride) hist[i] = 0;
}

__global__ __launch_bounds__(BLOCK) void k_hist(
    const unsigned* __restrict__ probbits, unsigned* __restrict__ hist,
    const unsigned* __restrict__ state, int level)
{
    if (state[4]) return;
    __shared__ unsigned h[NBINS];
    for (int i = threadIdx.x; i < NBINS; i += BLOCK) h[i] = 0;
    __syncthreads();
    unsigned pref = (level == 0) ? 0u : state[0];
    int stride = gridDim.x * BLOCK;
    for (int i = blockIdx.x * BLOCK + threadIdx.x; i < NPIX; i += stride) {
        unsigned pb = probbits[i];
        if (level == 0) atomicAdd(&h[pb >> 19], 1u);
        else if (level == 1) { if ((pb >> 19) == pref) atomicAdd(&h[(pb >> 6) & (NBINS - 1)], 1u); }
        else                 { if ((pb >> 6)  == pref) atomicAdd(&h[pb & 63u], 1u); }
    }
    __syncthreads();
    for (int i = threadIdx.x; i < NBINS; i += BLOCK) {
        unsigned c = h[i];
        if (c) atomicAdd(&hist[i], c);
    }
}

__global__ __launch_bounds__(BLOCK) void k_scan(
    unsigned* __restrict__ hist, unsigned* __restrict__ state, int level)
{
    if (state[4]) return;
    __shared__ unsigned h[NBINS];
    __shared__ unsigned wtot[4], wpre[4];
    int tid = threadIdx.x;
    for (int i = tid; i < NBINS; i += BLOCK) h[i] = hist[i];
    __syncthreads();

    unsigned vals[32];
    unsigned s = 0;
#pragma unroll
    for (int j = 0; j < 32; ++j) { vals[j] = h[tid * 32 + j]; s += vals[j]; }

    unsigned x = s;
    int lane = tid & 63, wid = tid >> 6;
    for (int d = 1; d < 64; d <<= 1) {
        unsigned y = __shfl_up(x, d);
        if (lane >= d) x += y;
    }
    if (lane == 63) wtot[wid] = x;
    __syncthreads();
    if (tid == 0) {
        unsigned a = 0;
        for (int i = 0; i < 4; ++i) { wpre[i] = a; a += wtot[i]; }
    }
    __syncthreads();
    unsigned excl = x + wpre[wid] - s;

    unsigned k = (level == 0) ? state[5] : state[1];
    unsigned pref = state[0];

    if (s > 0 && k >= excl && k < excl + s) {
        unsigned rem = k - excl;
        unsigned cum = 0, kn = 0; int bsel = 0; bool found = false;
#pragma unroll
        for (int j = 0; j < 32; ++j) {
            if (!found && rem < cum + vals[j]) { bsel = j; kn = rem - cum; found = true; }
            cum += vals[j];
        }
        unsigned bin = (unsigned)(tid * 32 + bsel);
        if (level == 0)      { state[0] = bin;                state[1] = kn; }
        else if (level == 1) { state[0] = (pref << 13) | bin; state[1] = kn; }
        else {
            unsigned tb = (pref << 6) | bin;    // exact k-th order stat bits
            state[2] = __float_as_uint(fmaxf(__uint_as_float(tb), 0.9f));
        }
    }
    __syncthreads();
    for (int i = tid; i < NBINS; i += BLOCK) hist[i] = 0;   // ready for next level
}

__global__ __launch_bounds__(BLOCK) void k_reduce_fb(
    const unsigned* __restrict__ probbits, const float* __restrict__ lossbuf,
    const unsigned* __restrict__ state, float* __restrict__ psum,
    unsigned* __restrict__ pcs)
{
    if (state[4]) return;
    unsigned tb = state[2];
    float s = 0.f; unsigned c = 0;
    int stride = gridDim.x * BLOCK;
    for (int i = blockIdx.x * BLOCK + threadIdx.x; i < NPIX; i += stride) {
        unsigned pb = probbits[i];
        float l = lossbuf[i];
        if (pb < tb) { s += l; c++; }      // uint cmp == float cmp for +floats
    }
#pragma unroll
    for (int d = 32; d > 0; d >>= 1) { s += __shfl_down(s, d); c += __shfl_down(c, d); }
    __shared__ float sd[4];
    __shared__ unsigned cd[4];
    int lane = threadIdx.x & 63, wid = threadIdx.x >> 6;
    if (lane == 0) { sd[wid] = s; cd[wid] = c; }
    __syncthreads();
    if (threadIdx.x == 0) {
        psum[blockIdx.x] = sd[0] + sd[1] + sd[2] + sd[3];
        pcs[blockIdx.x]  = cd[0] + cd[1] + cd[2] + cd[3];
    }
}

__global__ __launch_bounds__(BLOCK) void k_final_fb(
    const float* __restrict__ psum, const unsigned* __restrict__ pcs,
    const unsigned* __restrict__ state, float* __restrict__ out, int npart)
{
    if (state[4]) return;                 // common path: k_decide already wrote out
    __shared__ double red_d[4];
    __shared__ unsigned red_a[4];
    int tid = threadIdx.x;
    double ds = 0.0; unsigned ct = 0;
    for (int i = tid; i < npart; i += BLOCK) { ds += (double)psum[i]; ct += pcs[i]; }
#pragma unroll
    for (int d = 32; d > 0; d >>= 1) { ds += __shfl_down(ds, d); ct += __shfl_down(ct, d); }
    if ((tid & 63) == 0) { red_d[tid >> 6] = ds; red_a[tid >> 6] = ct; }
    __syncthreads();
    if (tid == 0) {
        double dt = red_d[0] + red_d[1] + red_d[2] + red_d[3];
        unsigned c = red_a[0] + red_a[1] + red_a[2] + red_a[3];
        out[0] = (float)(dt / (double)c);
    }
}

// ---------------------------------------------------------------------------
extern "C" void kernel_launch(void* const* d_in, const int* in_sizes, int n_in,
                              void* d_out, int out_size, void* d_ws, size_t ws_size,
                              hipStream_t stream)
{
    const float* predict = (const float*)d_in[0];
    const int*   target  = (const int*)d_in[1];
    const float* weight  = (const float*)d_in[2];
    char* ws = (char*)d_ws;
    float* out = (float*)d_out;

    float*    psum     = (float*)(ws + OFF_PSUM);
    unsigned* pcs      = (unsigned*)(ws + OFF_PCS);
    unsigned* pcv      = (unsigned*)(ws + OFF_PCV);
    unsigned* state    = (unsigned*)(ws + OFF_STATE);
    unsigned* probbits = (unsigned*)(ws + OFF_PROB);
    float*    lossbuf  = (float*)(ws + OFF_LOSS);
    unsigned* hist     = (unsigned*)(ws + OFF_HIST);

    k_main<<<GRID_MAIN, BLOCK, 0, stream>>>(predict, target, weight, psum, pcs, pcv);
    k_decide<<<1, BLOCK, 0, stream>>>(psum, pcs, pcv, state, out);
    // exact fallback chain (early-exits when threshold==0.9 path resolved)
    k_mat<<<1024, BLOCK, 0, stream>>>(predict, target, weight, state,
                                      probbits, lossbuf, hist);
    k_hist<<<512, BLOCK, 0, stream>>>(probbits, hist, state, 0);
    k_scan<<<1,   BLOCK, 0, stream>>>(hist, state, 0);
    k_hist<<<512, BLOCK, 0, stream>>>(probbits, hist, state, 1);
    k_scan<<<1,   BLOCK, 0, stream>>>(hist, state, 1);
    k_hist<<<512, BLOCK, 0, stream>>>(probbits, hist, state, 2);
    k_scan<<<1,   BLOCK, 0, stream>>>(hist, state, 2);
    k_reduce_fb<<<512, BLOCK, 0, stream>>>(probbits, lossbuf, state, psum, pcs);
    k_final_fb<<<1, BLOCK, 0, stream>>>(psum, pcs, state, out, 512);
}